// Round 17
// baseline (999.309 us; speedup 1.0000x reference)
//
#include <hip/hip_runtime.h>
#include <hip/hip_bf16.h>

typedef __hip_bfloat16 bf16;
typedef __attribute__((ext_vector_type(8))) short bf16x8;
typedef __attribute__((ext_vector_type(4))) float f32x4;
typedef __attribute__((ext_vector_type(4), aligned(4))) float f32x4u;  // unaligned-safe

#define NL 4
#define NH 12
#define C 768
#define T 1024
#define NB 2
#define BTOK 2048
#define V 50257
#define DH 64

__device__ __forceinline__ void gload16(const void* g, void* l) {
  __builtin_amdgcn_global_load_lds(
      (const __attribute__((address_space(1))) void*)g,
      (__attribute__((address_space(3))) void*)l, 16, 0, 0);
}

// raw barrier that does NOT drain vmem (global stores stay in flight)
__device__ __forceinline__ void lds_barrier() {
  asm volatile("s_waitcnt lgkmcnt(0)" ::: "memory");
  __builtin_amdgcn_s_barrier();
  __builtin_amdgcn_sched_barrier(0);
}

// ---------------- block reductions (256 threads = 4 waves) ----------------
__device__ __forceinline__ float block_sum(float v, float* red) {
#pragma unroll
  for (int off = 32; off; off >>= 1) v += __shfl_down(v, off);
  int lane = threadIdx.x & 63, wid = threadIdx.x >> 6;
  __syncthreads();
  if (lane == 0) red[wid] = v;
  __syncthreads();
  return red[0] + red[1] + red[2] + red[3];
}

// ---------------- fp32 -> bf16 transposed weight convert (64x64 tiles) -----
__global__ __launch_bounds__(256) void k_transpose_bf16(const float* __restrict__ W,
    bf16* __restrict__ Wt, int K, int N) {
  __shared__ float tile[64][69];
  long zoff = (long)blockIdx.z * K * N;
  W += zoff;
  Wt += zoff;
  int k0 = blockIdx.x * 64, n0 = blockIdx.y * 64;
  int tid = threadIdx.x;
  int rr = tid >> 4, rc = (tid & 15) * 4;
#pragma unroll
  for (int it = 0; it < 4; it++) {
    int k = it * 16 + rr;
    int gn = n0 + rc;
    const float* src = W + (long)(k0 + k) * N + gn;
    if (gn + 3 < N) {
      f32x4 v = *(const f32x4u*)src;
      tile[k][rc] = v[0]; tile[k][rc + 1] = v[1];
      tile[k][rc + 2] = v[2]; tile[k][rc + 3] = v[3];
    } else {
#pragma unroll
      for (int e = 0; e < 4; e++)
        tile[k][rc + e] = (gn + e < N) ? src[e] : 0.0f;
    }
  }
  __syncthreads();
  int wkc = tid & 7;
#pragma unroll
  for (int it = 0; it < 2; it++) {
    int n = it * 32 + (tid >> 3);
    int gn = n0 + n;
    if (gn < N) {
      union { bf16 h[8]; bf16x8 v; } u;
#pragma unroll
      for (int j = 0; j < 8; j++)
        u.h[j] = __float2bfloat16(tile[wkc * 8 + j][n]);
      *(bf16x8*)&Wt[(long)gn * K + k0 + wkc * 8] = u.v;
    }
  }
}

// ---------------- layernorm: fp32 in -> bf16 out ----------------
__global__ __launch_bounds__(256) void k_layernorm(const float* __restrict__ x,
    const float* __restrict__ w, const float* __restrict__ b, bf16* __restrict__ out) {
  __shared__ float red[4];
  long row = blockIdx.x;
  const float* xr = x + row * C;
  int t = threadIdx.x;
  float v0 = xr[t], v1 = xr[t + 256], v2 = xr[t + 512];
  float s = block_sum(v0 + v1 + v2, red);
  float mu = s * (1.0f / C);
  float d0 = v0 - mu, d1 = v1 - mu, d2 = v2 - mu;
  float vs = block_sum(d0 * d0 + d1 * d1 + d2 * d2, red);
  float inv = rsqrtf(vs * (1.0f / C) + 1e-5f);
  bf16* orow = out + row * C;
  orow[t]       = __float2bfloat16(d0 * inv * w[t]       + b[t]);
  orow[t + 256] = __float2bfloat16(d1 * inv * w[t + 256] + b[t + 256]);
  orow[t + 512] = __float2bfloat16(d2 * inv * w[t + 512] + b[t + 512]);
}

// ---------------- fused embed + layernorm (layer 0) ----------------
__global__ __launch_bounds__(256) void k_embed_ln(const int* __restrict__ idx,
    const float* __restrict__ wte, const float* __restrict__ wpe,
    const float* __restrict__ w, const float* __restrict__ b,
    float* __restrict__ x, bf16* __restrict__ out) {
  __shared__ float red[4];
  long row = blockIdx.x;
  int t = threadIdx.x;
  int tok = idx[row];
  int pos = (int)(row & (T - 1));
  const float* we = wte + (long)tok * C;
  const float* pe = wpe + (long)pos * C;
  float v0 = we[t] + pe[t], v1 = we[t + 256] + pe[t + 256], v2 = we[t + 512] + pe[t + 512];
  float* xr = x + row * C;
  xr[t] = v0; xr[t + 256] = v1; xr[t + 512] = v2;
  float s = block_sum(v0 + v1 + v2, red);
  float mu = s * (1.0f / C);
  float d0 = v0 - mu, d1 = v1 - mu, d2 = v2 - mu;
  float vs = block_sum(d0 * d0 + d1 * d1 + d2 * d2, red);
  float inv = rsqrtf(vs * (1.0f / C) + 1e-5f);
  bf16* orow = out + row * C;
  orow[t]       = __float2bfloat16(d0 * inv * w[t]       + b[t]);
  orow[t + 256] = __float2bfloat16(d1 * inv * w[t + 256] + b[t + 256]);
  orow[t + 512] = __float2bfloat16(d2 * inv * w[t + 512] + b[t + 512]);
}

// ------- fused causal flash attention: ONE WAVE PER BLOCK + T5 setprio -----
// grid (32, NB*NH, 2): blockIdx.x = pr*4 + g (16-row group); qt = z?15-pr:pr
__global__ __launch_bounds__(64) void k_attn(const bf16* __restrict__ q,
    const bf16* __restrict__ k, const bf16* __restrict__ vt,
    bf16* __restrict__ yb) {
  __shared__ __align__(16) bf16 Pl[16][72];  // per-wave P tile, +8 pad
  int pr = blockIdx.x >> 2, g = blockIdx.x & 3, bh = blockIdx.y;
  int b = bh / NH, h = bh % NH;
  int lane = threadIdx.x & 63;
  int l15 = lane & 15, hi = lane >> 4;
  const bf16* qbase = q + (long)bh * T * DH;
  const bf16* kbase = k + (long)bh * T * DH;
  const bf16* vbase = vt + (long)bh * DH * T;

  int qt = blockIdx.z ? (T / 64 - 1 - pr) : pr;
  int qrow = qt * 64 + g * 16 + l15;  // softmax-layout q (col of S^T)
  bf16x8 qf0 = *(const bf16x8*)(qbase + (long)qrow * DH + hi * 8);
  bf16x8 qf1 = *(const bf16x8*)(qbase + (long)qrow * DH + 32 + hi * 8);

  f32x4 accy[4] = {};               // y: row q=hi*4+rr, col d=j*16+l15
  float m_run = -1e30f, l_run = 0.f;

  int nkt = qt + 1;
  for (int kt = 0; kt < nkt; kt++) {
    int kv0 = kt * 64;
    f32x4 accs[4] = {};
#pragma unroll
    for (int kvi = 0; kvi < 4; kvi++) {
      const bf16* kr = kbase + (long)(kv0 + kvi * 16 + l15) * DH + hi * 8;
      bf16x8 kf0 = *(const bf16x8*)kr;
      bf16x8 kf1 = *(const bf16x8*)(kr + 32);
      __builtin_amdgcn_s_setprio(1);
      accs[kvi] = __builtin_amdgcn_mfma_f32_16x16x32_bf16(kf0, qf0, accs[kvi], 0, 0, 0);
      accs[kvi] = __builtin_amdgcn_mfma_f32_16x16x32_bf16(kf1, qf1, accs[kvi], 0, 0, 0);
      __builtin_amdgcn_s_setprio(0);
    }
    bool diag = (kt == qt);
    float p[4][4];
    float tmax = -1e30f;
#pragma unroll
    for (int kvi = 0; kvi < 4; kvi++)
#pragma unroll
      for (int rr = 0; rr < 4; rr++) {
        float s = accs[kvi][rr];
        if (diag && (kvi * 16 + hi * 4 + rr > g * 16 + l15)) s = -1e30f;
        p[kvi][rr] = s;
        tmax = fmaxf(tmax, s);
      }
    tmax = fmaxf(tmax, __shfl_xor(tmax, 16));
    tmax = fmaxf(tmax, __shfl_xor(tmax, 32));
    if (!__all(tmax - m_run <= 8.0f)) {  // wave-uniform
      float m_new = fmaxf(m_run, tmax);
      float scl = __expf(m_run - m_new);
      l_run *= scl;
#pragma unroll
      for (int rr = 0; rr < 4; rr++) {
        float sy = __shfl(scl, hi * 4 + rr);
#pragma unroll
        for (int j = 0; j < 4; j++) accy[j][rr] *= sy;
      }
      m_run = m_new;
    }
    float psum = 0.f;
#pragma unroll
    for (int kvi = 0; kvi < 4; kvi++)
#pragma unroll
      for (int rr = 0; rr < 4; rr++) {
        float e = __expf(p[kvi][rr] - m_run);
        p[kvi][rr] = e;
        psum += e;
      }
    psum += __shfl_xor(psum, 16);
    psum += __shfl_xor(psum, 32);
    l_run += psum;
#pragma unroll
    for (int kvi = 0; kvi < 4; kvi++) {
      union { bf16 hh[2]; unsigned u; } pk0, pk1;
      pk0.hh[0] = __float2bfloat16(p[kvi][0]);
      pk0.hh[1] = __float2bfloat16(p[kvi][1]);
      pk1.hh[0] = __float2bfloat16(p[kvi][2]);
      pk1.hh[1] = __float2bfloat16(p[kvi][3]);
      *(unsigned*)&Pl[l15][kvi * 16 + hi * 4]     = pk0.u;
      *(unsigned*)&Pl[l15][kvi * 16 + hi * 4 + 2] = pk1.u;
    }
#pragma unroll
    for (int c = 0; c < 2; c++) {
      bf16x8 pf = *(const bf16x8*)&Pl[l15][c * 32 + hi * 8];
      __builtin_amdgcn_s_setprio(1);
#pragma unroll
      for (int j = 0; j < 4; j++) {
        const bf16* vr = vbase + (long)(j * 16 + l15) * T + kv0 + c * 32 + hi * 8;
        bf16x8 vf = *(const bf16x8*)vr;
        accy[j] = __builtin_amdgcn_mfma_f32_16x16x32_bf16(pf, vf, accy[j], 0, 0, 0);
      }
      __builtin_amdgcn_s_setprio(0);
    }
  }
  float inv = 1.0f / l_run;
#pragma unroll
  for (int rr = 0; rr < 4; rr++) {
    float li = __shfl(inv, hi * 4 + rr);
    int qg = qt * 64 + g * 16 + hi * 4 + rr;
#pragma unroll
    for (int j = 0; j < 4; j++)
      yb[((long)(b * T + qg)) * C + h * DH + j * 16 + l15] =
          __float2bfloat16(accy[j][rr] * li);
  }
}

// ================= 8-phase 256x256 head GEMM (M=2048,N=V,K=768) ============
__global__ __launch_bounds__(512, 1) void k_head(const bf16* __restrict__ A,
    const bf16* __restrict__ B, float* __restrict__ Cv) {
  __shared__ __align__(16) char lds[131072];
  int hw = blockIdx.y * 8 + blockIdx.x;          // grid (8, 197), nwg=1576
  int L = (hw & 7) * 197 + (hw >> 3);            // bijective XCD chunk
  int mt = L & 7, nt = L >> 3;
  int m0 = mt * 256, n0 = nt * 256;
  int tid = threadIdx.x, lane = tid & 63, wid = tid >> 6;
  int wm = wid >> 2, wn = wid & 3;
  int l15 = lane & 15, hi = lane >> 4, l7 = lane & 7;
  int sg = (lane & 7) ^ (lane >> 3);             // pre-swizzled src granule
  int srA = wid * 8 + (lane >> 3);               // staging row
  const bf16* Ab = A + (long)(m0 + srA) * 768 + sg * 8;
  const bf16* Bb = B + (long)(n0 + srA) * 768 + sg * 8;  // OOB tail lands in ws
  auto STAGE = [&](int tile, int h) {            // h: 0=A0 1=A1 2=B0 3=B1
    char* dst = lds + (tile & 1) * 65536 + h * 16384 + wid * 1024;
    const bf16* src = (h < 2 ? Ab : Bb) + (long)((h & 1) * 128) * 768 + tile * 64;
    gload16(src, dst);
    gload16(src + 64 * 768, dst + 8192);
  };
  f32x4 acc[8][4] = {};
  STAGE(0, 0); STAGE(0, 1); STAGE(0, 2); STAGE(0, 3); STAGE(1, 0);
  asm volatile("s_waitcnt vmcnt(2)" ::: "memory");
  __builtin_amdgcn_s_barrier();
  int bro = (wn & 1) * 64;
  int g0 = (hi ^ l7) * 16, g1 = ((4 + hi) ^ l7) * 16;
  for (int t = 0; t < 12; t++) {
    char* ha = lds + (t & 1) * 65536 + wm * 16384;
    char* hb = lds + (t & 1) * 65536 + 32768 + (wn >> 1) * 16384;
    bf16x8 af[4], bv[4];
#pragma unroll
    for (int mf = 0; mf < 4; mf++)
      af[mf] = *(const bf16x8*)(ha + (mf * 16 + l15) * 128 + g0);
#pragma unroll
    for (int nf = 0; nf < 4; nf++)
      bv[nf] = *(const bf16x8*)(hb + (bro + nf * 16 + l15) * 128 + g0);
    if (t + 1 < 12) { STAGE(t + 1, 1); STAGE(t + 1, 2); }
    __builtin_amdgcn_s_barrier();
    __builtin_amdgcn_s_setprio(1);
#pragma unroll
    for (int mf = 0; mf < 4; mf++)
#pragma unroll
      for (int nf = 0; nf < 4; nf++)
        acc[mf][nf] = __builtin_amdgcn_mfma_f32_16x16x32_bf16(af[mf], bv[nf], acc[mf][nf], 0, 0, 0);
    __builtin_amdgcn_s_setprio(0);
    __builtin_amdgcn_s_barrier();
#pragma unroll
    for (int mf = 0; mf < 4; mf++)
      af[mf] = *(const bf16x8*)(ha + ((mf + 4) * 16 + l15) * 128 + g0);
    if (t + 1 < 12) STAGE(t + 1, 3);
    __builtin_amdgcn_s_barrier();
    __builtin_amdgcn_s_setprio(1);
#pragma unroll
    for (int mf = 0; mf < 4; mf++)
#pragma unroll
      for (int nf = 0; nf < 4; nf++)
        acc[mf + 4][nf] = __builtin_amdgcn_mfma_f32_16x16x32_bf16(af[mf], bv[nf], acc[mf + 4][nf], 0, 0, 0);
    __builtin_amdgcn_s_setprio(0);
    __builtin_amdgcn_s_barrier();
#pragma unroll
    for (int mf = 0; mf < 4; mf++)
      af[mf] = *(const bf16x8*)(ha + (mf * 16 + l15) * 128 + g1);
#pragma unroll
    for (int nf = 0; nf < 4; nf++)
      bv[nf] = *(const bf16x8*)(hb + (bro + nf * 16 + l15) * 128 + g1);
    __builtin_amdgcn_s_barrier();
    __builtin_amdgcn_s_setprio(1);
#pragma unroll
    for (int mf = 0; mf < 4; mf++)
#pragma unroll
      for (int nf = 0; nf < 4; nf++)
        acc[mf][nf] = __builtin_amdgcn_mfma_f32_16x16x32_bf16(af[mf], bv[nf], acc[mf][nf], 0, 0, 0);
    __builtin_amdgcn_s_setprio(0);
    __builtin_amdgcn_s_barrier();
#pragma unroll
    for (int mf = 0; mf < 4; mf++)
      af[mf] = *(const bf16x8*)(ha + ((mf + 4) * 16 + l15) * 128 + g1);
    if (t + 2 < 12) STAGE(t + 2, 0);
    __builtin_amdgcn_s_barrier();
    __builtin_amdgcn_s_setprio(1);
#pragma unroll
    for (int mf = 0; mf < 4; mf++)
#pragma unroll
      for (int nf = 0; nf < 4; nf++)
        acc[mf + 4][nf] = __builtin_amdgcn_mfma_f32_16x16x32_bf16(af[mf], bv[nf], acc[mf + 4][nf], 0, 0, 0);
    __builtin_amdgcn_s_setprio(0);
    if (t < 11) {
      if (t + 2 < 12) asm volatile("s_waitcnt vmcnt(2)" ::: "memory");
      else            asm volatile("s_waitcnt vmcnt(0)" ::: "memory");
      __builtin_amdgcn_s_barrier();
    }
  }
  // ---- epilogue: 2 mf-slices per LDS round; raw barriers (no vmem drain) ----
  lds_barrier();
  float* Cst = (float*)lds;
#pragma unroll
  for (int rnd = 0; rnd < 4; rnd++) {
#pragma unroll
    for (int mfl = 0; mfl < 2; mfl++) {
      int mf = rnd * 2 + mfl;
#pragma unroll
      for (int nf = 0; nf < 4; nf++)
#pragma unroll
        for (int rr = 0; rr < 4; rr++)
          Cst[(wm * 32 + mfl * 16 + hi * 4 + rr) * 260 + wn * 64 + nf * 16 + l15] =
              acc[mf][nf][rr];
    }
    lds_barrier();
#pragma unroll
    for (int s = 0; s < 8; s++) {
      int gid = tid + s * 512;           // 0..4095
      int r = gid >> 6, g = gid & 63;    // row 0..63, 4-col granule
      int grow = m0 + (r >> 5) * 128 + (rnd * 2 + ((r >> 4) & 1)) * 16 + (r & 15);
      int gcol = n0 + g * 4;
      f32x4 vv = *(const f32x4*)&Cst[r * 260 + g * 4];
      float* dst = Cv + (long)grow * V + gcol;
      if (gcol + 3 < V) {
        *(f32x4u*)dst = vv;
      } else {
#pragma unroll
        for (int e = 0; e < 4; e++)
          if (gcol + e < V) dst[e] = vv[e];
      }
    }
    lds_barrier();
  }
}

// ------- layer GEMM: BM=64, BN=128, BK=64, depth-2 pipeline, XCD swizzle ----
// EPI 2: bf16 out, gelu(acc+bias). EPI 5: qkv split-repack.
#define SBK 64
template <int EPI>
__global__ __launch_bounds__(256) void k_gemm_s(const bf16* __restrict__ A,
    const bf16* __restrict__ B, const float* __restrict__ bias,
    void* __restrict__ Cv, int M, int N, int K, int lda, int ldb, int ldc,
    void* __restrict__ Cv2, void* __restrict__ Cv3) {
  __shared__ __align__(16) bf16 As[2][64][SBK];   // 16 KiB
  __shared__ __align__(16) bf16 Bs[2][128][SBK];  // 32 KiB
  int nwg = gridDim.x * gridDim.y;
  int hw = blockIdx.y * gridDim.x + blockIdx.x;
  int logical = (hw & 7) * (nwg >> 3) + (hw >> 3);
  int bx = logical % gridDim.x, by = logical / gridDim.x;
  int m0 = bx * 64, n0 = by * 128;
  int tid = threadIdx.x;
  int lane = tid & 63, w = tid >> 6;
  int l15 = lane & 15, hi = lane >> 4, l7 = lane & 7;
  int srow = lane >> 3;                 // 0..7
  int sgr = lane & 7;
  int scol = ((sgr ^ srow) << 3);       // pre-swizzled source col (elements)
  f32x4 acc[4][2] = {};
  const bf16* Ag = A + (long)(m0 + w * 8 + srow) * lda + scol;
  const bf16* Bg = B + (long)(n0 + w * 8 + srow) * ldb + scol;
  int NT = K / SBK;
  auto STAGE = [&](int t) {
    int k0 = t * SBK, b = t & 1;
    gload16(Ag + k0,            &As[b][w * 8][0]);
    gload16(Ag + k0 + 32 * lda, &As[b][w * 8 + 32][0]);
    gload16(Bg + k0,            &Bs[b][w * 8][0]);
    gload16(Bg + k0 + 32 * ldb, &Bs[b][w * 8 + 32][0]);
    gload16(Bg + k0 + 64 * ldb, &Bs[b][w * 8 + 64][0]);
    gload16(Bg + k0 + 96 * ldb, &Bs[b][w * 8 + 96][0]);
  };
  STAGE(0);
  STAGE(1);
  int c0 = (hi ^ l7) << 3, c1 = ((4 + hi) ^ l7) << 3;  // kk0/kk1 read cols
  for (int t = 0; t < NT; t++) {
    int b = t & 1;
    if (t + 1 < NT) asm volatile("s_waitcnt vmcnt(6)" ::: "memory");
    else            asm volatile("s_waitcnt vmcnt(0)" ::: "memory");
    __builtin_amdgcn_s_barrier();
    bf16x8 a0[4], a1[4], b0[2], b1[2];
#pragma unroll
    for (int i = 0; i < 4; i++) {
      a0[i] = *(const bf16x8*)&As[b][i * 16 + l15][c0];
      a1[i] = *(const bf16x8*)&As[b][i * 16 + l15][c1];
    }
#pragma unroll
    for (int j = 0; j < 2; j++) {
      b0[j] = *(const bf16x8*)&Bs[b][w * 32 + j * 16 + l15][c0];
      b1[j] = *(const bf16x8*)&Bs[b][w * 32 + j * 16 + l15][c1];
    }
    asm volatile("s_waitcnt lgkmcnt(0)" ::: "memory");
    __builtin_amdgcn_s_barrier();
    if (t + 2 < NT) STAGE(t + 2);
    __builtin_amdgcn_s_setprio(1);
#pragma unroll
    for (int i = 0; i < 4; i++)
#pragma unroll
      for (int j = 0; j < 2; j++) {
        acc[i][j] = __builtin_amdgcn_mfma_f32_16x16x32_bf16(a0[i], b0[j], acc[i][j], 0, 0, 0);
        acc[i][j] = __builtin_amdgcn_mfma_f32_16x16x32_bf16(a1[i], b1[j], acc[i][j], 0, 0, 0);
      }
    __builtin_amdgcn_s_setprio(0);
  }
#pragma unroll
  for (int j = 0; j < 2; j++) {
    int gn = n0 + w * 32 + j * 16 + l15;
    float bv = bias[gn];
#pragma unroll
    for (int i = 0; i < 4; i++)
#pragma unroll
      for (int rr = 0; rr < 4; rr++) {
        int gm = m0 + i * 16 + hi * 4 + rr;
        float v = acc[i][j][rr] + bv;
        if constexpr (EPI == 2) {
          float u = 0.7978845608028654f * (v + 0.044715f * v * v * v);
          u = fminf(fmaxf(u, -15.f), 15.f);
          float e2 = __expf(2.f * u);
          float th = (e2 - 1.f) / (e2 + 1.f);
          ((bf16*)Cv)[(long)gm * ldc + gn] = __float2bfloat16(0.5f * v * (1.f + th));
        } else if constexpr (EPI == 5) {
          int gb = gm >> 10, gt = gm & 1023;
          int which = gn / C;
          int r = gn - which * C;
          int h = r >> 6, d = r & 63;
          long bh = (long)(gb * NH + h);
          if (which == 0)
            ((bf16*)Cv)[(bh * T + gt) * DH + d] = __float2bfloat16(v * 0.125f);
          else if (which == 1)
            ((bf16*)Cv2)[(bh * T + gt) * DH + d] = __float2bfloat16(v);
          else
            ((bf16*)Cv3)[(bh * DH + d) * T + gt] = __float2bfloat16(v);
        }
      }
  }
}

// ------- small GEMM: BM=64, BN=64, BK=64, depth-2, residual (proj/fc2) -----
__global__ __launch_bounds__(256) void k_gemm_s64(const bf16* __restrict__ A,
    const bf16* __restrict__ B, const float* __restrict__ bias,
    float* __restrict__ Cx, int M, int N, int K, int lda, int ldb, int ldc) {
  __shared__ __align__(16) bf16 As[2][64][64];   // 16 KiB
  __shared__ __align__(16) bf16 Bs[2][64][64];   // 16 KiB
  int nwg = gridDim.x * gridDim.y;
  int hw = blockIdx.y * gridDim.x + blockIdx.x;
  int logical = (hw & 7) * (nwg >> 3) + (hw >> 3);
  int bx = logical % gridDim.x, by = logical / gridDim.x;
  int m0 = bx * 64, n0 = by * 64;
  int tid = threadIdx.x;
  int lane = tid & 63, w = tid >> 6;
  int l15 = lane & 15, hi = lane >> 4, l7 = lane & 7;
  int srow = lane >> 3;                 // 0..7
  int sgr = lane & 7;
  int scol = ((sgr ^ srow) << 3);       // pre-swizzled source col (elements)
  f32x4 acc[4] = {};
  const bf16* Ag = A + (long)(m0 + w * 8 + srow) * lda + scol;
  const bf16* Bg = B + (long)(n0 + w * 8 + srow) * ldb + scol;
  int NT = K / 64;
  auto STAGE = [&](int t) {
    int k0 = t * 64, b = t & 1;
    gload16(Ag + k0,            &As[b][w * 8][0]);
    gload16(Ag + k0 + 32 * lda, &As[b][w * 8 + 32][0]);
    gload16(Bg + k0,            &Bs[b][w * 8][0]);
    gload16(Bg + k0 + 32 * ldb, &Bs[b][w * 8 + 32][0]);
  };
  STAGE(0);
  STAGE(1);
  int c0 = (hi ^ l7) << 3, c1 = ((4 + hi) ^ l7) << 3;  // kk0/kk1 read cols
  for (int t = 0; t < NT; t++) {
    int b = t & 1;
    if (t + 1 < NT) asm volatile("s_waitcnt vmcnt(4)" ::: "memory");
    else            asm volatile("s_waitcnt vmcnt(0)" ::: "memory");
    __builtin_amdgcn_s_barrier();
    bf16x8 a0[4], a1[4], b0, b1;
#pragma unroll
    for (int i = 0; i < 4; i++) {
      a0[i] = *(const bf16x8*)&As[b][i * 16 + l15][c0];
      a1[i] = *(const bf16x8*)&As[b][i * 16 + l15][c1];
    }
    b0 = *(const bf16x8*)&Bs[b][w * 16 + l15][c0];
    b1 = *(const bf16x8*)&Bs[b][w * 16 + l15][c1];
    asm volatile("s_waitcnt lgkmcnt(0)" ::: "memory");
    __builtin_amdgcn_s_barrier();
    if (t + 2 < NT) STAGE(t + 2);
    __builtin_amdgcn_s_setprio(1);
#pragma unroll
    for (int i = 0; i < 4; i++) {
      acc[i] = __builtin_amdgcn_mfma_f32_16x16x32_bf16(a0[i], b0, acc[i], 0, 0, 0);
      acc[i] = __builtin_amdgcn_mfma_f32_16x16x32_bf16(a1[i], b1, acc[i], 0, 0, 0);
    }
    __builtin_amdgcn_s_setprio(0);
  }
  int gn = n0 + w * 16 + l15;
  float bv = bias[gn];
#pragma unroll
  for (int i = 0; i < 4; i++)
#pragma unroll
    for (int rr = 0; rr < 4; rr++) {
      int gm = m0 + i * 16 + hi * 4 + rr;
      long off = (long)gm * ldc + gn;
      Cx[off] = acc[i][rr] + bv + Cx[off];
    }
}

extern "C" void kernel_launch(void* const* d_in, const int* in_sizes, int n_in,
                              void* d_out, int out_size, void* d_ws, size_t ws_size,
                              hipStream_t stream) {
  const int*   idx    = (const int*)d_in[0];
  const float* wte    = (const float*)d_in[1];
  const float* wpe    = (const float*)d_in[2];
  const float* ln1_w  = (const float*)d_in[3];
  const float* ln1_b  = (const float*)d_in[4];
  const float* qkv_w  = (const float*)d_in[5];
  const float* qkv_b  = (const float*)d_in[6];
  const float* proj_w = (const float*)d_in[7];
  const float* proj_b = (const float*)d_in[8];
  const float* ln2_w  = (const float*)d_in[9];
  const float* ln2_b  = (const float*)d_in[10];
  const float* fc_w   = (const float*)d_in[11];
  const float* fc_b   = (const float*)d_in[12];
  const float* fc2_w  = (const float*)d_in[13];
  const float* fc2_b  = (const float*)d_in[14];
  const float* lnf_w  = (const float*)d_in[15];
  const float* lnf_b  = (const float*)d_in[16];
  const float* head_w = (const float*)d_in[17];
  (void)in_sizes; (void)n_in; (void)out_size; (void)ws_size;

  char* base = (char*)d_ws;
  size_t off = 0;
  auto alloc = [&](size_t bytes) -> void* {
    void* p = base + off;
    off = (off + bytes + 255) & ~(size_t)255;
    return p;
  };
  bf16* wt_qkv  = (bf16*)alloc((size_t)NL * 3 * C * C * 2);
  bf16* wt_proj = (bf16*)alloc((size_t)NL * C * C * 2);
  bf16* wt_fc   = (bf16*)alloc((size_t)NL * 4 * C * C * 2);
  bf16* wt_fc2  = (bf16*)alloc((size_t)NL * 4 * C * C * 2);
  bf16* wt_head = (bf16*)alloc((size_t)V * C * 2);
  float* x      = (float*)alloc((size_t)BTOK * C * 4);   // absorbs head OOB reads
  bf16*  xb     = (bf16*)alloc((size_t)BTOK * C * 2);
  bf16*  qb     = (bf16*)alloc((size_t)NB * NH * T * DH * 2);
  bf16*  kb     = (bf16*)alloc((size_t)NB * NH * T * DH * 2);
  bf16*  vtb    = (bf16*)alloc((size_t)NB * NH * T * DH * 2);
  bf16*  yb     = (bf16*)alloc((size_t)BTOK * C * 2);
  bf16*  mbuf   = (bf16*)alloc((size_t)BTOK * 4 * C * 2);

  k_transpose_bf16<<<dim3(12, 36, NL), 256, 0, stream>>>(qkv_w, wt_qkv, C, 3 * C);
  k_transpose_bf16<<<dim3(12, 12, NL), 256, 0, stream>>>(proj_w, wt_proj, C, C);
  k_transpose_bf16<<<dim3(12, 48, NL), 256, 0, stream>>>(fc_w, wt_fc, C, 4 * C);
  k_transpose_bf16<<<dim3(48, 12, NL), 256, 0, stream>>>(fc2_w, wt_fc2, 4 * C, C);
  k_transpose_bf16<<<dim3(12, (V + 63) / 64, 1), 256, 0, stream>>>(head_w, wt_head, C, V);

  k_embed_ln<<<BTOK, 256, 0, stream>>>(idx, wte, wpe, ln1_w, ln1_b, x, xb);

  for (int l = 0; l < NL; l++) {
    if (l > 0)
      k_layernorm<<<BTOK, 256, 0, stream>>>(x, ln1_w + l * C, ln1_b + l * C, xb);
    k_gemm_s<5><<<dim3(32, 18), 256, 0, stream>>>(xb, wt_qkv + (long)l * 3 * C * C,
        qkv_b + l * 3 * C, qb, BTOK, 3 * C, C, C, C, 0, kb, vtb);
    k_attn<<<dim3(32, NB * NH, 2), 64, 0, stream>>>(qb, kb, vtb, yb);
    k_gemm_s64<<<dim3(32, 12), 256, 0, stream>>>(yb, wt_proj + (long)l * C * C,
        proj_b + l * C, x, BTOK, C, C, C, C, C);
    k_layernorm<<<BTOK, 256, 0, stream>>>(x, ln2_w + l * C, ln2_b + l * C, xb);
    k_gemm_s<2><<<dim3(32, 24), 256, 0, stream>>>(xb, wt_fc + (long)l * 4 * C * C,
        fc_b + l * 4 * C, mbuf, BTOK, 4 * C, C, C, C, 4 * C, nullptr, nullptr);
    k_gemm_s64<<<dim3(32, 12), 256, 0, stream>>>(mbuf, wt_fc2 + (long)l * 4 * C * C,
        fc2_b + l * C, x, BTOK, C, 4 * C, 4 * C, 4 * C, C);
  }
  k_layernorm<<<BTOK, 256, 0, stream>>>(x, lnf_w, lnf_b, xb);
  k_head<<<dim3(8, 197), 512, 0, stream>>>(xb, wt_head, (float*)d_out);
}

// Round 18
// 936.267 us; speedup vs baseline: 1.0673x; 1.0673x over previous
//
#include <hip/hip_runtime.h>
#include <hip/hip_bf16.h>

typedef __hip_bfloat16 bf16;
typedef __attribute__((ext_vector_type(8))) short bf16x8;
typedef __attribute__((ext_vector_type(4))) float f32x4;
typedef __attribute__((ext_vector_type(4), aligned(4))) float f32x4u;  // unaligned-safe

#define NL 4
#define NH 12
#define C 768
#define T 1024
#define NB 2
#define BTOK 2048
#define V 50257
#define DH 64

__device__ __forceinline__ void gload16(const void* g, void* l) {
  __builtin_amdgcn_global_load_lds(
      (const __attribute__((address_space(1))) void*)g,
      (__attribute__((address_space(3))) void*)l, 16, 0, 0);
}

// raw barrier that does NOT drain vmem (global stores stay in flight)
__device__ __forceinline__ void lds_barrier() {
  asm volatile("s_waitcnt lgkmcnt(0)" ::: "memory");
  __builtin_amdgcn_s_barrier();
  __builtin_amdgcn_sched_barrier(0);
}

// ---------------- block reductions (256 threads = 4 waves) ----------------
__device__ __forceinline__ float block_sum(float v, float* red) {
#pragma unroll
  for (int off = 32; off; off >>= 1) v += __shfl_down(v, off);
  int lane = threadIdx.x & 63, wid = threadIdx.x >> 6;
  __syncthreads();
  if (lane == 0) red[wid] = v;
  __syncthreads();
  return red[0] + red[1] + red[2] + red[3];
}

// ---------------- fp32 -> bf16 transposed weight convert (64x64 tiles) -----
__global__ __launch_bounds__(256) void k_transpose_bf16(const float* __restrict__ W,
    bf16* __restrict__ Wt, int K, int N) {
  __shared__ float tile[64][69];
  long zoff = (long)blockIdx.z * K * N;
  W += zoff;
  Wt += zoff;
  int k0 = blockIdx.x * 64, n0 = blockIdx.y * 64;
  int tid = threadIdx.x;
  int rr = tid >> 4, rc = (tid & 15) * 4;
#pragma unroll
  for (int it = 0; it < 4; it++) {
    int k = it * 16 + rr;
    int gn = n0 + rc;
    const float* src = W + (long)(k0 + k) * N + gn;
    if (gn + 3 < N) {
      f32x4 v = *(const f32x4u*)src;
      tile[k][rc] = v[0]; tile[k][rc + 1] = v[1];
      tile[k][rc + 2] = v[2]; tile[k][rc + 3] = v[3];
    } else {
#pragma unroll
      for (int e = 0; e < 4; e++)
        tile[k][rc + e] = (gn + e < N) ? src[e] : 0.0f;
    }
  }
  __syncthreads();
  int wkc = tid & 7;
#pragma unroll
  for (int it = 0; it < 2; it++) {
    int n = it * 32 + (tid >> 3);
    int gn = n0 + n;
    if (gn < N) {
      union { bf16 h[8]; bf16x8 v; } u;
#pragma unroll
      for (int j = 0; j < 8; j++)
        u.h[j] = __float2bfloat16(tile[wkc * 8 + j][n]);
      *(bf16x8*)&Wt[(long)gn * K + k0 + wkc * 8] = u.v;
    }
  }
}

// ---------------- layernorm: fp32 in -> bf16 out ----------------
__global__ __launch_bounds__(256) void k_layernorm(const float* __restrict__ x,
    const float* __restrict__ w, const float* __restrict__ b, bf16* __restrict__ out) {
  __shared__ float red[4];
  long row = blockIdx.x;
  const float* xr = x + row * C;
  int t = threadIdx.x;
  float v0 = xr[t], v1 = xr[t + 256], v2 = xr[t + 512];
  float s = block_sum(v0 + v1 + v2, red);
  float mu = s * (1.0f / C);
  float d0 = v0 - mu, d1 = v1 - mu, d2 = v2 - mu;
  float vs = block_sum(d0 * d0 + d1 * d1 + d2 * d2, red);
  float inv = rsqrtf(vs * (1.0f / C) + 1e-5f);
  bf16* orow = out + row * C;
  orow[t]       = __float2bfloat16(d0 * inv * w[t]       + b[t]);
  orow[t + 256] = __float2bfloat16(d1 * inv * w[t + 256] + b[t + 256]);
  orow[t + 512] = __float2bfloat16(d2 * inv * w[t + 512] + b[t + 512]);
}

// ---------------- fused embed + layernorm (layer 0) ----------------
__global__ __launch_bounds__(256) void k_embed_ln(const int* __restrict__ idx,
    const float* __restrict__ wte, const float* __restrict__ wpe,
    const float* __restrict__ w, const float* __restrict__ b,
    float* __restrict__ x, bf16* __restrict__ out) {
  __shared__ float red[4];
  long row = blockIdx.x;
  int t = threadIdx.x;
  int tok = idx[row];
  int pos = (int)(row & (T - 1));
  const float* we = wte + (long)tok * C;
  const float* pe = wpe + (long)pos * C;
  float v0 = we[t] + pe[t], v1 = we[t + 256] + pe[t + 256], v2 = we[t + 512] + pe[t + 512];
  float* xr = x + row * C;
  xr[t] = v0; xr[t + 256] = v1; xr[t + 512] = v2;
  float s = block_sum(v0 + v1 + v2, red);
  float mu = s * (1.0f / C);
  float d0 = v0 - mu, d1 = v1 - mu, d2 = v2 - mu;
  float vs = block_sum(d0 * d0 + d1 * d1 + d2 * d2, red);
  float inv = rsqrtf(vs * (1.0f / C) + 1e-5f);
  bf16* orow = out + row * C;
  orow[t]       = __float2bfloat16(d0 * inv * w[t]       + b[t]);
  orow[t + 256] = __float2bfloat16(d1 * inv * w[t + 256] + b[t + 256]);
  orow[t + 512] = __float2bfloat16(d2 * inv * w[t + 512] + b[t + 512]);
}

// ------- fused causal flash attention: ONE WAVE PER BLOCK (tail smoothing) --
// grid (32, NB*NH, 2): blockIdx.x = pr*4 + g (16-row group); qt = z?15-pr:pr
__global__ __launch_bounds__(64) void k_attn(const bf16* __restrict__ q,
    const bf16* __restrict__ k, const bf16* __restrict__ vt,
    bf16* __restrict__ yb) {
  __shared__ __align__(16) bf16 Pl[16][72];  // per-wave P tile, +8 pad
  int pr = blockIdx.x >> 2, g = blockIdx.x & 3, bh = blockIdx.y;
  int b = bh / NH, h = bh % NH;
  int lane = threadIdx.x & 63;
  int l15 = lane & 15, hi = lane >> 4;
  const bf16* qbase = q + (long)bh * T * DH;
  const bf16* kbase = k + (long)bh * T * DH;
  const bf16* vbase = vt + (long)bh * DH * T;

  int qt = blockIdx.z ? (T / 64 - 1 - pr) : pr;
  int qrow = qt * 64 + g * 16 + l15;  // softmax-layout q (col of S^T)
  bf16x8 qf0 = *(const bf16x8*)(qbase + (long)qrow * DH + hi * 8);
  bf16x8 qf1 = *(const bf16x8*)(qbase + (long)qrow * DH + 32 + hi * 8);

  f32x4 accy[4] = {};               // y: row q=hi*4+rr, col d=j*16+l15
  float m_run = -1e30f, l_run = 0.f;

  int nkt = qt + 1;
  for (int kt = 0; kt < nkt; kt++) {
    int kv0 = kt * 64;
    f32x4 accs[4] = {};
#pragma unroll
    for (int kvi = 0; kvi < 4; kvi++) {
      const bf16* kr = kbase + (long)(kv0 + kvi * 16 + l15) * DH + hi * 8;
      bf16x8 kf0 = *(const bf16x8*)kr;
      bf16x8 kf1 = *(const bf16x8*)(kr + 32);
      accs[kvi] = __builtin_amdgcn_mfma_f32_16x16x32_bf16(kf0, qf0, accs[kvi], 0, 0, 0);
      accs[kvi] = __builtin_amdgcn_mfma_f32_16x16x32_bf16(kf1, qf1, accs[kvi], 0, 0, 0);
    }
    bool diag = (kt == qt);
    float p[4][4];
    float tmax = -1e30f;
#pragma unroll
    for (int kvi = 0; kvi < 4; kvi++)
#pragma unroll
      for (int rr = 0; rr < 4; rr++) {
        float s = accs[kvi][rr];
        if (diag && (kvi * 16 + hi * 4 + rr > g * 16 + l15)) s = -1e30f;
        p[kvi][rr] = s;
        tmax = fmaxf(tmax, s);
      }
    tmax = fmaxf(tmax, __shfl_xor(tmax, 16));
    tmax = fmaxf(tmax, __shfl_xor(tmax, 32));
    if (!__all(tmax - m_run <= 8.0f)) {  // wave-uniform
      float m_new = fmaxf(m_run, tmax);
      float scl = __expf(m_run - m_new);
      l_run *= scl;
#pragma unroll
      for (int rr = 0; rr < 4; rr++) {
        float sy = __shfl(scl, hi * 4 + rr);
#pragma unroll
        for (int j = 0; j < 4; j++) accy[j][rr] *= sy;
      }
      m_run = m_new;
    }
    float psum = 0.f;
#pragma unroll
    for (int kvi = 0; kvi < 4; kvi++)
#pragma unroll
      for (int rr = 0; rr < 4; rr++) {
        float e = __expf(p[kvi][rr] - m_run);
        p[kvi][rr] = e;
        psum += e;
      }
    psum += __shfl_xor(psum, 16);
    psum += __shfl_xor(psum, 32);
    l_run += psum;
#pragma unroll
    for (int kvi = 0; kvi < 4; kvi++) {
      union { bf16 hh[2]; unsigned u; } pk0, pk1;
      pk0.hh[0] = __float2bfloat16(p[kvi][0]);
      pk0.hh[1] = __float2bfloat16(p[kvi][1]);
      pk1.hh[0] = __float2bfloat16(p[kvi][2]);
      pk1.hh[1] = __float2bfloat16(p[kvi][3]);
      *(unsigned*)&Pl[l15][kvi * 16 + hi * 4]     = pk0.u;
      *(unsigned*)&Pl[l15][kvi * 16 + hi * 4 + 2] = pk1.u;
    }
#pragma unroll
    for (int c = 0; c < 2; c++) {
      bf16x8 pf = *(const bf16x8*)&Pl[l15][c * 32 + hi * 8];
#pragma unroll
      for (int j = 0; j < 4; j++) {
        const bf16* vr = vbase + (long)(j * 16 + l15) * T + kv0 + c * 32 + hi * 8;
        bf16x8 vf = *(const bf16x8*)vr;
        accy[j] = __builtin_amdgcn_mfma_f32_16x16x32_bf16(pf, vf, accy[j], 0, 0, 0);
      }
    }
  }
  float inv = 1.0f / l_run;
#pragma unroll
  for (int rr = 0; rr < 4; rr++) {
    float li = __shfl(inv, hi * 4 + rr);
    int qg = qt * 64 + g * 16 + hi * 4 + rr;
#pragma unroll
    for (int j = 0; j < 4; j++)
      yb[((long)(b * T + qg)) * C + h * DH + j * 16 + l15] =
          __float2bfloat16(accy[j][rr] * li);
  }
}

// ================= 8-phase 256x256 head GEMM (M=2048,N=V,K=768) ============
__global__ __launch_bounds__(512, 1) void k_head(const bf16* __restrict__ A,
    const bf16* __restrict__ B, float* __restrict__ Cv) {
  __shared__ __align__(16) char lds[131072];
  int hw = blockIdx.y * 8 + blockIdx.x;          // grid (8, 197), nwg=1576
  int L = (hw & 7) * 197 + (hw >> 3);            // bijective XCD chunk
  int mt = L & 7, nt = L >> 3;
  int m0 = mt * 256, n0 = nt * 256;
  int tid = threadIdx.x, lane = tid & 63, wid = tid >> 6;
  int wm = wid >> 2, wn = wid & 3;
  int l15 = lane & 15, hi = lane >> 4, l7 = lane & 7;
  int sg = (lane & 7) ^ (lane >> 3);             // pre-swizzled src granule
  int srA = wid * 8 + (lane >> 3);               // staging row
  const bf16* Ab = A + (long)(m0 + srA) * 768 + sg * 8;
  const bf16* Bb = B + (long)(n0 + srA) * 768 + sg * 8;  // OOB tail lands in ws
  auto STAGE = [&](int tile, int h) {            // h: 0=A0 1=A1 2=B0 3=B1
    char* dst = lds + (tile & 1) * 65536 + h * 16384 + wid * 1024;
    const bf16* src = (h < 2 ? Ab : Bb) + (long)((h & 1) * 128) * 768 + tile * 64;
    gload16(src, dst);
    gload16(src + 64 * 768, dst + 8192);
  };
  f32x4 acc[8][4] = {};
  STAGE(0, 0); STAGE(0, 1); STAGE(0, 2); STAGE(0, 3); STAGE(1, 0);
  asm volatile("s_waitcnt vmcnt(2)" ::: "memory");
  __builtin_amdgcn_s_barrier();
  int bro = (wn & 1) * 64;
  int g0 = (hi ^ l7) * 16, g1 = ((4 + hi) ^ l7) * 16;
  for (int t = 0; t < 12; t++) {
    char* ha = lds + (t & 1) * 65536 + wm * 16384;
    char* hb = lds + (t & 1) * 65536 + 32768 + (wn >> 1) * 16384;
    bf16x8 af[4], bv[4];
#pragma unroll
    for (int mf = 0; mf < 4; mf++)
      af[mf] = *(const bf16x8*)(ha + (mf * 16 + l15) * 128 + g0);
#pragma unroll
    for (int nf = 0; nf < 4; nf++)
      bv[nf] = *(const bf16x8*)(hb + (bro + nf * 16 + l15) * 128 + g0);
    if (t + 1 < 12) { STAGE(t + 1, 1); STAGE(t + 1, 2); }
    __builtin_amdgcn_s_barrier();
    __builtin_amdgcn_s_setprio(1);
#pragma unroll
    for (int mf = 0; mf < 4; mf++)
#pragma unroll
      for (int nf = 0; nf < 4; nf++)
        acc[mf][nf] = __builtin_amdgcn_mfma_f32_16x16x32_bf16(af[mf], bv[nf], acc[mf][nf], 0, 0, 0);
    __builtin_amdgcn_s_setprio(0);
    __builtin_amdgcn_s_barrier();
#pragma unroll
    for (int mf = 0; mf < 4; mf++)
      af[mf] = *(const bf16x8*)(ha + ((mf + 4) * 16 + l15) * 128 + g0);
    if (t + 1 < 12) STAGE(t + 1, 3);
    __builtin_amdgcn_s_barrier();
    __builtin_amdgcn_s_setprio(1);
#pragma unroll
    for (int mf = 0; mf < 4; mf++)
#pragma unroll
      for (int nf = 0; nf < 4; nf++)
        acc[mf + 4][nf] = __builtin_amdgcn_mfma_f32_16x16x32_bf16(af[mf], bv[nf], acc[mf + 4][nf], 0, 0, 0);
    __builtin_amdgcn_s_setprio(0);
    __builtin_amdgcn_s_barrier();
#pragma unroll
    for (int mf = 0; mf < 4; mf++)
      af[mf] = *(const bf16x8*)(ha + (mf * 16 + l15) * 128 + g1);
#pragma unroll
    for (int nf = 0; nf < 4; nf++)
      bv[nf] = *(const bf16x8*)(hb + (bro + nf * 16 + l15) * 128 + g1);
    __builtin_amdgcn_s_barrier();
    __builtin_amdgcn_s_setprio(1);
#pragma unroll
    for (int mf = 0; mf < 4; mf++)
#pragma unroll
      for (int nf = 0; nf < 4; nf++)
        acc[mf][nf] = __builtin_amdgcn_mfma_f32_16x16x32_bf16(af[mf], bv[nf], acc[mf][nf], 0, 0, 0);
    __builtin_amdgcn_s_setprio(0);
    __builtin_amdgcn_s_barrier();
#pragma unroll
    for (int mf = 0; mf < 4; mf++)
      af[mf] = *(const bf16x8*)(ha + ((mf + 4) * 16 + l15) * 128 + g1);
    if (t + 2 < 12) STAGE(t + 2, 0);
    __builtin_amdgcn_s_barrier();
    __builtin_amdgcn_s_setprio(1);
#pragma unroll
    for (int mf = 0; mf < 4; mf++)
#pragma unroll
      for (int nf = 0; nf < 4; nf++)
        acc[mf + 4][nf] = __builtin_amdgcn_mfma_f32_16x16x32_bf16(af[mf], bv[nf], acc[mf + 4][nf], 0, 0, 0);
    __builtin_amdgcn_s_setprio(0);
    if (t < 11) {
      if (t + 2 < 12) asm volatile("s_waitcnt vmcnt(2)" ::: "memory");
      else            asm volatile("s_waitcnt vmcnt(0)" ::: "memory");
      __builtin_amdgcn_s_barrier();
    }
  }
  // ---- epilogue: 2 mf-slices per LDS round; raw barriers (no vmem drain) ----
  lds_barrier();
  float* Cst = (float*)lds;
#pragma unroll
  for (int rnd = 0; rnd < 4; rnd++) {
#pragma unroll
    for (int mfl = 0; mfl < 2; mfl++) {
      int mf = rnd * 2 + mfl;
#pragma unroll
      for (int nf = 0; nf < 4; nf++)
#pragma unroll
        for (int rr = 0; rr < 4; rr++)
          Cst[(wm * 32 + mfl * 16 + hi * 4 + rr) * 260 + wn * 64 + nf * 16 + l15] =
              acc[mf][nf][rr];
    }
    lds_barrier();
#pragma unroll
    for (int s = 0; s < 8; s++) {
      int gid = tid + s * 512;           // 0..4095
      int r = gid >> 6, g = gid & 63;    // row 0..63, 4-col granule
      int grow = m0 + (r >> 5) * 128 + (rnd * 2 + ((r >> 4) & 1)) * 16 + (r & 15);
      int gcol = n0 + g * 4;
      f32x4 vv = *(const f32x4*)&Cst[r * 260 + g * 4];
      float* dst = Cv + (long)grow * V + gcol;
      if (gcol + 3 < V) {
        *(f32x4u*)dst = vv;
      } else {
#pragma unroll
        for (int e = 0; e < 4; e++)
          if (gcol + e < V) dst[e] = vv[e];
      }
    }
    lds_barrier();
  }
}

// ------- layer GEMM: BM=64, BN=128, BK=64, depth-2 pipeline, XCD swizzle ----
// EPI 2: bf16 out, gelu(acc+bias). EPI 5: qkv split-repack.
#define SBK 64
template <int EPI>
__global__ __launch_bounds__(256) void k_gemm_s(const bf16* __restrict__ A,
    const bf16* __restrict__ B, const float* __restrict__ bias,
    void* __restrict__ Cv, int M, int N, int K, int lda, int ldb, int ldc,
    void* __restrict__ Cv2, void* __restrict__ Cv3) {
  __shared__ __align__(16) bf16 As[2][64][SBK];   // 16 KiB
  __shared__ __align__(16) bf16 Bs[2][128][SBK];  // 32 KiB
  int nwg = gridDim.x * gridDim.y;
  int hw = blockIdx.y * gridDim.x + blockIdx.x;
  int logical = (hw & 7) * (nwg >> 3) + (hw >> 3);
  int bx = logical % gridDim.x, by = logical / gridDim.x;
  int m0 = bx * 64, n0 = by * 128;
  int tid = threadIdx.x;
  int lane = tid & 63, w = tid >> 6;
  int l15 = lane & 15, hi = lane >> 4, l7 = lane & 7;
  int srow = lane >> 3;                 // 0..7
  int sgr = lane & 7;
  int scol = ((sgr ^ srow) << 3);       // pre-swizzled source col (elements)
  f32x4 acc[4][2] = {};
  const bf16* Ag = A + (long)(m0 + w * 8 + srow) * lda + scol;
  const bf16* Bg = B + (long)(n0 + w * 8 + srow) * ldb + scol;
  int NT = K / SBK;
  auto STAGE = [&](int t) {
    int k0 = t * SBK, b = t & 1;
    gload16(Ag + k0,            &As[b][w * 8][0]);
    gload16(Ag + k0 + 32 * lda, &As[b][w * 8 + 32][0]);
    gload16(Bg + k0,            &Bs[b][w * 8][0]);
    gload16(Bg + k0 + 32 * ldb, &Bs[b][w * 8 + 32][0]);
    gload16(Bg + k0 + 64 * ldb, &Bs[b][w * 8 + 64][0]);
    gload16(Bg + k0 + 96 * ldb, &Bs[b][w * 8 + 96][0]);
  };
  STAGE(0);
  STAGE(1);
  int c0 = (hi ^ l7) << 3, c1 = ((4 + hi) ^ l7) << 3;  // kk0/kk1 read cols
  for (int t = 0; t < NT; t++) {
    int b = t & 1;
    if (t + 1 < NT) asm volatile("s_waitcnt vmcnt(6)" ::: "memory");
    else            asm volatile("s_waitcnt vmcnt(0)" ::: "memory");
    __builtin_amdgcn_s_barrier();
    bf16x8 a0[4], a1[4], b0[2], b1[2];
#pragma unroll
    for (int i = 0; i < 4; i++) {
      a0[i] = *(const bf16x8*)&As[b][i * 16 + l15][c0];
      a1[i] = *(const bf16x8*)&As[b][i * 16 + l15][c1];
    }
#pragma unroll
    for (int j = 0; j < 2; j++) {
      b0[j] = *(const bf16x8*)&Bs[b][w * 32 + j * 16 + l15][c0];
      b1[j] = *(const bf16x8*)&Bs[b][w * 32 + j * 16 + l15][c1];
    }
    asm volatile("s_waitcnt lgkmcnt(0)" ::: "memory");
    __builtin_amdgcn_s_barrier();
    if (t + 2 < NT) STAGE(t + 2);
    __builtin_amdgcn_s_setprio(1);
#pragma unroll
    for (int i = 0; i < 4; i++)
#pragma unroll
      for (int j = 0; j < 2; j++) {
        acc[i][j] = __builtin_amdgcn_mfma_f32_16x16x32_bf16(a0[i], b0[j], acc[i][j], 0, 0, 0);
        acc[i][j] = __builtin_amdgcn_mfma_f32_16x16x32_bf16(a1[i], b1[j], acc[i][j], 0, 0, 0);
      }
    __builtin_amdgcn_s_setprio(0);
  }
#pragma unroll
  for (int j = 0; j < 2; j++) {
    int gn = n0 + w * 32 + j * 16 + l15;
    float bv = bias[gn];
#pragma unroll
    for (int i = 0; i < 4; i++)
#pragma unroll
      for (int rr = 0; rr < 4; rr++) {
        int gm = m0 + i * 16 + hi * 4 + rr;
        float v = acc[i][j][rr] + bv;
        if constexpr (EPI == 2) {
          float u = 0.7978845608028654f * (v + 0.044715f * v * v * v);
          u = fminf(fmaxf(u, -15.f), 15.f);
          float e2 = __expf(2.f * u);
          float th = (e2 - 1.f) / (e2 + 1.f);
          ((bf16*)Cv)[(long)gm * ldc + gn] = __float2bfloat16(0.5f * v * (1.f + th));
        } else if constexpr (EPI == 5) {
          int gb = gm >> 10, gt = gm & 1023;
          int which = gn / C;
          int r = gn - which * C;
          int h = r >> 6, d = r & 63;
          long bh = (long)(gb * NH + h);
          if (which == 0)
            ((bf16*)Cv)[(bh * T + gt) * DH + d] = __float2bfloat16(v * 0.125f);
          else if (which == 1)
            ((bf16*)Cv2)[(bh * T + gt) * DH + d] = __float2bfloat16(v);
          else
            ((bf16*)Cv3)[(bh * DH + d) * T + gt] = __float2bfloat16(v);
        }
      }
  }
}

// ------- small GEMM: BM=64, BN=64, BK=64, depth-2, residual (proj/fc2) -----
__global__ __launch_bounds__(256) void k_gemm_s64(const bf16* __restrict__ A,
    const bf16* __restrict__ B, const float* __restrict__ bias,
    float* __restrict__ Cx, int M, int N, int K, int lda, int ldb, int ldc) {
  __shared__ __align__(16) bf16 As[2][64][64];   // 16 KiB
  __shared__ __align__(16) bf16 Bs[2][64][64];   // 16 KiB
  int nwg = gridDim.x * gridDim.y;
  int hw = blockIdx.y * gridDim.x + blockIdx.x;
  int logical = (hw & 7) * (nwg >> 3) + (hw >> 3);
  int bx = logical % gridDim.x, by = logical / gridDim.x;
  int m0 = bx * 64, n0 = by * 64;
  int tid = threadIdx.x;
  int lane = tid & 63, w = tid >> 6;
  int l15 = lane & 15, hi = lane >> 4, l7 = lane & 7;
  int srow = lane >> 3;                 // 0..7
  int sgr = lane & 7;
  int scol = ((sgr ^ srow) << 3);       // pre-swizzled source col (elements)
  f32x4 acc[4] = {};
  const bf16* Ag = A + (long)(m0 + w * 8 + srow) * lda + scol;
  const bf16* Bg = B + (long)(n0 + w * 8 + srow) * ldb + scol;
  int NT = K / 64;
  auto STAGE = [&](int t) {
    int k0 = t * 64, b = t & 1;
    gload16(Ag + k0,            &As[b][w * 8][0]);
    gload16(Ag + k0 + 32 * lda, &As[b][w * 8 + 32][0]);
    gload16(Bg + k0,            &Bs[b][w * 8][0]);
    gload16(Bg + k0 + 32 * ldb, &Bs[b][w * 8 + 32][0]);
  };
  STAGE(0);
  STAGE(1);
  int c0 = (hi ^ l7) << 3, c1 = ((4 + hi) ^ l7) << 3;  // kk0/kk1 read cols
  for (int t = 0; t < NT; t++) {
    int b = t & 1;
    if (t + 1 < NT) asm volatile("s_waitcnt vmcnt(4)" ::: "memory");
    else            asm volatile("s_waitcnt vmcnt(0)" ::: "memory");
    __builtin_amdgcn_s_barrier();
    bf16x8 a0[4], a1[4], b0, b1;
#pragma unroll
    for (int i = 0; i < 4; i++) {
      a0[i] = *(const bf16x8*)&As[b][i * 16 + l15][c0];
      a1[i] = *(const bf16x8*)&As[b][i * 16 + l15][c1];
    }
    b0 = *(const bf16x8*)&Bs[b][w * 16 + l15][c0];
    b1 = *(const bf16x8*)&Bs[b][w * 16 + l15][c1];
    asm volatile("s_waitcnt lgkmcnt(0)" ::: "memory");
    __builtin_amdgcn_s_barrier();
    if (t + 2 < NT) STAGE(t + 2);
    __builtin_amdgcn_s_setprio(1);
#pragma unroll
    for (int i = 0; i < 4; i++) {
      acc[i] = __builtin_amdgcn_mfma_f32_16x16x32_bf16(a0[i], b0, acc[i], 0, 0, 0);
      acc[i] = __builtin_amdgcn_mfma_f32_16x16x32_bf16(a1[i], b1, acc[i], 0, 0, 0);
    }
    __builtin_amdgcn_s_setprio(0);
  }
  int gn = n0 + w * 16 + l15;
  float bv = bias[gn];
#pragma unroll
  for (int i = 0; i < 4; i++)
#pragma unroll
    for (int rr = 0; rr < 4; rr++) {
      int gm = m0 + i * 16 + hi * 4 + rr;
      long off = (long)gm * ldc + gn;
      Cx[off] = acc[i][rr] + bv + Cx[off];
    }
}

extern "C" void kernel_launch(void* const* d_in, const int* in_sizes, int n_in,
                              void* d_out, int out_size, void* d_ws, size_t ws_size,
                              hipStream_t stream) {
  const int*   idx    = (const int*)d_in[0];
  const float* wte    = (const float*)d_in[1];
  const float* wpe    = (const float*)d_in[2];
  const float* ln1_w  = (const float*)d_in[3];
  const float* ln1_b  = (const float*)d_in[4];
  const float* qkv_w  = (const float*)d_in[5];
  const float* qkv_b  = (const float*)d_in[6];
  const float* proj_w = (const float*)d_in[7];
  const float* proj_b = (const float*)d_in[8];
  const float* ln2_w  = (const float*)d_in[9];
  const float* ln2_b  = (const float*)d_in[10];
  const float* fc_w   = (const float*)d_in[11];
  const float* fc_b   = (const float*)d_in[12];
  const float* fc2_w  = (const float*)d_in[13];
  const float* fc2_b  = (const float*)d_in[14];
  const float* lnf_w  = (const float*)d_in[15];
  const float* lnf_b  = (const float*)d_in[16];
  const float* head_w = (const float*)d_in[17];
  (void)in_sizes; (void)n_in; (void)out_size; (void)ws_size;

  char* base = (char*)d_ws;
  size_t off = 0;
  auto alloc = [&](size_t bytes) -> void* {
    void* p = base + off;
    off = (off + bytes + 255) & ~(size_t)255;
    return p;
  };
  bf16* wt_qkv  = (bf16*)alloc((size_t)NL * 3 * C * C * 2);
  bf16* wt_proj = (bf16*)alloc((size_t)NL * C * C * 2);
  bf16* wt_fc   = (bf16*)alloc((size_t)NL * 4 * C * C * 2);
  bf16* wt_fc2  = (bf16*)alloc((size_t)NL * 4 * C * C * 2);
  bf16* wt_head = (bf16*)alloc((size_t)V * C * 2);
  float* x      = (float*)alloc((size_t)BTOK * C * 4);   // absorbs head OOB reads
  bf16*  xb     = (bf16*)alloc((size_t)BTOK * C * 2);
  bf16*  qb     = (bf16*)alloc((size_t)NB * NH * T * DH * 2);
  bf16*  kb     = (bf16*)alloc((size_t)NB * NH * T * DH * 2);
  bf16*  vtb    = (bf16*)alloc((size_t)NB * NH * T * DH * 2);
  bf16*  yb     = (bf16*)alloc((size_t)BTOK * C * 2);
  bf16*  mbuf   = (bf16*)alloc((size_t)BTOK * 4 * C * 2);

  k_transpose_bf16<<<dim3(12, 36, NL), 256, 0, stream>>>(qkv_w, wt_qkv, C, 3 * C);
  k_transpose_bf16<<<dim3(12, 12, NL), 256, 0, stream>>>(proj_w, wt_proj, C, C);
  k_transpose_bf16<<<dim3(12, 48, NL), 256, 0, stream>>>(fc_w, wt_fc, C, 4 * C);
  k_transpose_bf16<<<dim3(48, 12, NL), 256, 0, stream>>>(fc2_w, wt_fc2, 4 * C, C);
  k_transpose_bf16<<<dim3(12, (V + 63) / 64, 1), 256, 0, stream>>>(head_w, wt_head, C, V);

  k_embed_ln<<<BTOK, 256, 0, stream>>>(idx, wte, wpe, ln1_w, ln1_b, x, xb);

  for (int l = 0; l < NL; l++) {
    if (l > 0)
      k_layernorm<<<BTOK, 256, 0, stream>>>(x, ln1_w + l * C, ln1_b + l * C, xb);
    k_gemm_s<5><<<dim3(32, 18), 256, 0, stream>>>(xb, wt_qkv + (long)l * 3 * C * C,
        qkv_b + l * 3 * C, qb, BTOK, 3 * C, C, C, C, 0, kb, vtb);
    k_attn<<<dim3(32, NB * NH, 2), 64, 0, stream>>>(qb, kb, vtb, yb);
    k_gemm_s64<<<dim3(32, 12), 256, 0, stream>>>(yb, wt_proj + (long)l * C * C,
        proj_b + l * C, x, BTOK, C, C, C, C, C);
    k_layernorm<<<BTOK, 256, 0, stream>>>(x, ln2_w + l * C, ln2_b + l * C, xb);
    k_gemm_s<2><<<dim3(32, 24), 256, 0, stream>>>(xb, wt_fc + (long)l * 4 * C * C,
        fc_b + l * 4 * C, mbuf, BTOK, 4 * C, C, C, C, 4 * C, nullptr, nullptr);
    k_gemm_s64<<<dim3(32, 12), 256, 0, stream>>>(mbuf, wt_fc2 + (long)l * 4 * C * C,
        fc2_b + l * C, x, BTOK, C, 4 * C, 4 * C, 4 * C, C);
  }
  k_layernorm<<<BTOK, 256, 0, stream>>>(x, lnf_w, lnf_b, xb);
  k_head<<<dim3(8, 197), 512, 0, stream>>>(xb, wt_head, (float*)d_out);
}